// Round 1
// baseline (303.506 us; speedup 1.0000x reference)
//
#include <hip/hip_runtime.h>
#include <cstdint>
#include <cstddef>

typedef __bf16 bf16;
typedef __bf16 bf16x4 __attribute__((ext_vector_type(4)));
typedef __bf16 bf16x8 __attribute__((ext_vector_type(8)));
typedef float  f32x4  __attribute__((ext_vector_type(4)));

#define BATCH 4
#define SEQ   2048
#define DIM   1024
#define NQKV  3072

// RNE float -> bf16 (avoid reliance on __bf16 arithmetic conversions)
__device__ __forceinline__ bf16 to_bf16(float f) {
    unsigned u = __builtin_bit_cast(unsigned, f);
    u += 0x7fffu + ((u >> 16) & 1u);
    unsigned short h = (unsigned short)(u >> 16);
    return __builtin_bit_cast(bf16, h);
}

// async global->LDS, 16B per lane. LDS dest is wave-uniform base + lane*16.
__device__ __forceinline__ void load16_lds(const bf16* g, bf16* l) {
    __builtin_amdgcn_global_load_lds(
        (__attribute__((address_space(1))) void*)(g),
        (__attribute__((address_space(3))) void*)(l),
        16, 0, 0);
}

// ---------------------------------------------------------------------------
// Core: C[128x128] block of A(MxK, row-major) @ B^T where B stored (NxK, row-major).
// 256 threads = 4 waves, each wave does 64x64 via 4x4 mfma_f32_16x16x32_bf16.
// ---------------------------------------------------------------------------
__device__ __forceinline__ void gemm_bt_core(
    const bf16* __restrict__ Abase,   // already offset to block row * 128
    const bf16* __restrict__ Bbase,   // already offset to block col * 128
    int K, int lda, int ldb,
    bf16* As, bf16* Bs, f32x4 acc[4][4])
{
    const int tid  = threadIdx.x;
    const int lane = tid & 63;
    const int wave = tid >> 6;
    const int wm   = (wave >> 1) * 64;
    const int wn   = (wave & 1) * 64;
    const int r16  = lane & 15;
    const int q8   = (lane >> 4) * 8;       // k-offset within fragment
    const int srow = tid >> 2;              // staging row 0..63 (+64 second issue)
    const int scol = (tid & 3) * 8;         // staging k-offset (8 bf16 = 16B)
    const int lb   = (tid & 192) * 8;       // wave-uniform LDS element base, iter 0

    for (int k0 = 0; k0 < K; k0 += 32) {
        __syncthreads();   // previous iteration's ds_reads done before overwrite
        const bf16* ga = Abase + (size_t)srow * lda + (k0 + scol);
        const bf16* gb = Bbase + (size_t)srow * ldb + (k0 + scol);
        load16_lds(ga,                     As + lb);
        load16_lds(ga + (size_t)64 * lda,  As + 2048 + lb);
        load16_lds(gb,                     Bs + lb);
        load16_lds(gb + (size_t)64 * ldb,  Bs + 2048 + lb);
        __syncthreads();   // vmcnt(0) drained here -> tiles ready

        bf16x8 af[4], bfr[4];
#pragma unroll
        for (int i = 0; i < 4; ++i)
            af[i] = *(const bf16x8*)(As + (wm + i * 16 + r16) * 32 + q8);
#pragma unroll
        for (int i = 0; i < 4; ++i)
            bfr[i] = *(const bf16x8*)(Bs + (wn + i * 16 + r16) * 32 + q8);
#pragma unroll
        for (int mi = 0; mi < 4; ++mi)
#pragma unroll
            for (int ni = 0; ni < 4; ++ni)
                acc[mi][ni] = __builtin_amdgcn_mfma_f32_16x16x32_bf16(
                    af[mi], bfr[ni], acc[mi][ni], 0, 0, 0);
    }
}

// ---------------------------------------------------------------------------
// GEMM 1: [8192,1024] x [3072,1024]^T -> Q/K/V bf16, each [8192,1024]
// ---------------------------------------------------------------------------
__global__ __launch_bounds__(256) void qkv_gemm(
    const bf16* __restrict__ X, const bf16* __restrict__ Wt,
    bf16* __restrict__ Q, bf16* __restrict__ Kp, bf16* __restrict__ V)
{
    __shared__ bf16 As[4096];
    __shared__ bf16 Bs[4096];
    f32x4 acc[4][4] = {};

    const bf16* Ab = X  + (size_t)blockIdx.y * 128 * DIM;
    const bf16* Bb = Wt + (size_t)blockIdx.x * 128 * DIM;
    gemm_bt_core(Ab, Bb, DIM, DIM, DIM, As, Bs, acc);

    const int lane = threadIdx.x & 63;
    const int wave = threadIdx.x >> 6;
    const int wm = (wave >> 1) * 64, wn = (wave & 1) * 64;
    const int rowBase = blockIdx.y * 128 + wm + ((lane >> 4) * 4);
    const int colBase = blockIdx.x * 128 + wn + (lane & 15);
#pragma unroll
    for (int mi = 0; mi < 4; ++mi) {
#pragma unroll
        for (int ni = 0; ni < 4; ++ni) {
            const int col = colBase + ni * 16;
            const int sel = col >> 10;         // 0:Q 1:K 2:V
            const int e   = col & 1023;
            bf16* dst = (sel == 0) ? Q : (sel == 1) ? Kp : V;
#pragma unroll
            for (int r = 0; r < 4; ++r) {
                const int m = rowBase + mi * 16 + r;   // m = b*SEQ + s (flat)
                dst[(size_t)m * DIM + e] = to_bf16(acc[mi][ni][r]);
            }
        }
    }
}

// ---------------------------------------------------------------------------
// GEMM 2/3: batched bt-GEMM, fp32 output with scale
// grid = (N/128, M/128, batch)
// ---------------------------------------------------------------------------
__global__ __launch_bounds__(256) void gemm_bt_f32(
    const bf16* __restrict__ A, const bf16* __restrict__ Bm, float* __restrict__ C,
    int K, int lda, int ldb, int ldc, float scale,
    long strA, long strB, long strC)
{
    __shared__ bf16 As[4096];
    __shared__ bf16 Bs[4096];
    f32x4 acc[4][4] = {};

    const bf16* Ab = A  + (size_t)blockIdx.z * strA + (size_t)blockIdx.y * 128 * lda;
    const bf16* Bb = Bm + (size_t)blockIdx.z * strB + (size_t)blockIdx.x * 128 * ldb;
    float* Cb = C + (size_t)blockIdx.z * strC;
    gemm_bt_core(Ab, Bb, K, lda, ldb, As, Bs, acc);

    const int lane = threadIdx.x & 63;
    const int wave = threadIdx.x >> 6;
    const int wm = (wave >> 1) * 64, wn = (wave & 1) * 64;
    const int rowBase = blockIdx.y * 128 + wm + ((lane >> 4) * 4);
    const int colBase = blockIdx.x * 128 + wn + (lane & 15);
#pragma unroll
    for (int mi = 0; mi < 4; ++mi)
#pragma unroll
        for (int ni = 0; ni < 4; ++ni) {
            const int col = colBase + ni * 16;
#pragma unroll
            for (int r = 0; r < 4; ++r)
                Cb[(size_t)(rowBase + mi * 16 + r) * ldc + col] = acc[mi][ni][r] * scale;
        }
}

// ---------------------------------------------------------------------------
// fp32 -> bf16 cast (x), vectorized
// ---------------------------------------------------------------------------
__global__ __launch_bounds__(256) void cvt_x(const float* __restrict__ x, bf16* __restrict__ y) {
    const size_t i = ((size_t)blockIdx.x * 256 + threadIdx.x) * 4;
    const float4 v = *(const float4*)(x + i);
    bf16x4 o = { to_bf16(v.x), to_bf16(v.y), to_bf16(v.z), to_bf16(v.w) };
    *(bf16x4*)(y + i) = o;
}

// ---------------------------------------------------------------------------
// weights: [1024,1024] fp32 (K-major rows) -> transposed bf16 [3072,1024] (N rows, K contiguous)
// grid = (32, 32, 3), block = (32, 8)
// ---------------------------------------------------------------------------
__global__ void cvt_w_t(const float* __restrict__ wq, const float* __restrict__ wk,
                        const float* __restrict__ wv, bf16* __restrict__ Wt)
{
    __shared__ float tile[32][33];
    const int sel = blockIdx.z;
    const float* w = (sel == 0) ? wq : (sel == 1) ? wk : wv;
    const int n0 = blockIdx.x * 32;
    const int k0 = blockIdx.y * 32;
    const int tx = threadIdx.x, ty = threadIdx.y;
#pragma unroll
    for (int j = 0; j < 32; j += 8)
        tile[ty + j][tx] = w[(size_t)(k0 + ty + j) * 1024 + n0 + tx];
    __syncthreads();
    bf16* dst = Wt + (size_t)sel * 1024 * 1024;
#pragma unroll
    for (int j = 0; j < 32; j += 8)
        dst[(size_t)(n0 + ty + j) * 1024 + k0 + tx] = to_bf16(tile[tx][ty + j]);
}

// ---------------------------------------------------------------------------
// V [b][s][d] -> Vt [b][d][s], bf16. grid = (1024/32, 2048/32, 4), block (32,8)
// ---------------------------------------------------------------------------
__global__ void transpose_v(const bf16* __restrict__ V, bf16* __restrict__ Vt) {
    __shared__ bf16 tile[32][33];
    const int b  = blockIdx.z;
    const int d0 = blockIdx.x * 32;
    const int s0 = blockIdx.y * 32;
    const int tx = threadIdx.x, ty = threadIdx.y;
    const bf16* Vb  = V  + (size_t)b * SEQ * DIM;
    bf16* Vtb = Vt + (size_t)b * DIM * SEQ;
#pragma unroll
    for (int j = 0; j < 32; j += 8)
        tile[ty + j][tx] = Vb[(size_t)(s0 + ty + j) * DIM + d0 + tx];
    __syncthreads();
#pragma unroll
    for (int j = 0; j < 32; j += 8)
        Vtb[(size_t)(d0 + ty + j) * SEQ + s0 + tx] = tile[tx][ty + j];
}

// ---------------------------------------------------------------------------
// row softmax over 2048 fp32 scores -> bf16 P. grid = (8192), block = 256
// ---------------------------------------------------------------------------
__global__ __launch_bounds__(256) void softmax_k(const float* __restrict__ Sc,
                                                 bf16* __restrict__ P)
{
    __shared__ float red[8];
    const size_t row = blockIdx.x;
    const float* src = Sc + row * (size_t)SEQ;
    const int tid = threadIdx.x;
    const int lane = tid & 63;
    const int wave = tid >> 6;

    const float4 v0 = *(const float4*)(src + tid * 4);
    const float4 v1 = *(const float4*)(src + 1024 + tid * 4);
    float e[8] = { v0.x, v0.y, v0.z, v0.w, v1.x, v1.y, v1.z, v1.w };

    float mx = e[0];
#pragma unroll
    for (int i = 1; i < 8; ++i) mx = fmaxf(mx, e[i]);
#pragma unroll
    for (int off = 32; off >= 1; off >>= 1) mx = fmaxf(mx, __shfl_xor(mx, off));
    if (lane == 0) red[wave] = mx;
    __syncthreads();
    mx = fmaxf(fmaxf(red[0], red[1]), fmaxf(red[2], red[3]));

    float sum = 0.f;
#pragma unroll
    for (int i = 0; i < 8; ++i) { e[i] = __expf(e[i] - mx); sum += e[i]; }
#pragma unroll
    for (int off = 32; off >= 1; off >>= 1) sum += __shfl_xor(sum, off);
    if (lane == 0) red[4 + wave] = sum;
    __syncthreads();
    sum = (red[4] + red[5]) + (red[6] + red[7]);
    const float inv = 1.0f / sum;

    bf16x4 o0 = { to_bf16(e[0] * inv), to_bf16(e[1] * inv), to_bf16(e[2] * inv), to_bf16(e[3] * inv) };
    bf16x4 o1 = { to_bf16(e[4] * inv), to_bf16(e[5] * inv), to_bf16(e[6] * inv), to_bf16(e[7] * inv) };
    *(bf16x4*)(P + row * (size_t)SEQ + tid * 4)        = o0;
    *(bf16x4*)(P + row * (size_t)SEQ + 1024 + tid * 4) = o1;
}

// ---------------------------------------------------------------------------
extern "C" void kernel_launch(void* const* d_in, const int* in_sizes, int n_in,
                              void* d_out, int out_size, void* d_ws, size_t ws_size,
                              hipStream_t stream)
{
    const float* x  = (const float*)d_in[0];
    const float* wq = (const float*)d_in[1];
    const float* wk = (const float*)d_in[2];
    const float* wv = (const float*)d_in[3];
    float* out = (float*)d_out;
    char* ws = (char*)d_ws;

    // workspace layout (bytes)
    bf16*  xb = (bf16*)(ws);                      // 16 MB  [8192,1024]
    bf16*  Wt = (bf16*)(ws + 16777216);           //  6 MB  [3072,1024]
    bf16*  Q  = (bf16*)(ws + 23068672);           // 16 MB
    bf16*  Kp = (bf16*)(ws + 39845888);           // 16 MB
    bf16*  V  = (bf16*)(ws + 56623104);           // 16 MB
    bf16*  Vt = (bf16*)(ws + 73400320);           // 16 MB
    float* Sc = (float*)(ws + 90177536);          // 64 MB  [4,2048,2048] fp32
    bf16*  P  = (bf16*)(ws + 23068672);           // 32 MB, aliases Q+K (dead after scores GEMM)

    cvt_x<<<dim3(8192), dim3(256), 0, stream>>>(x, xb);
    cvt_w_t<<<dim3(32, 32, 3), dim3(32, 8), 0, stream>>>(wq, wk, wv, Wt);

    // QKV projection: M=8192, N=3072, K=1024
    qkv_gemm<<<dim3(24, 64), dim3(256), 0, stream>>>(xb, Wt, Q, Kp, V);

    transpose_v<<<dim3(32, 64, 4), dim3(32, 8), 0, stream>>>(V, Vt);

    // scores = Q @ K^T * (1/32): per batch M=N=2048, K=1024
    gemm_bt_f32<<<dim3(16, 16, 4), dim3(256), 0, stream>>>(
        Q, Kp, Sc, 1024, 1024, 1024, 2048, 0.03125f,
        (long)SEQ * DIM, (long)SEQ * DIM, (long)SEQ * SEQ);

    softmax_k<<<dim3(BATCH * SEQ), dim3(256), 0, stream>>>(Sc, P);

    // out = P @ Vt^T: per batch M=2048, N=1024, K=2048
    gemm_bt_f32<<<dim3(8, 16, 4), dim3(256), 0, stream>>>(
        P, Vt, out, 2048, 2048, 2048, 1024, 1.0f,
        (long)SEQ * SEQ, (long)DIM * SEQ, (long)SEQ * DIM);
}

// Round 2
// 294.509 us; speedup vs baseline: 1.0305x; 1.0305x over previous
//
#include <hip/hip_runtime.h>
#include <cstdint>
#include <cstddef>

typedef __bf16 bf16;
typedef __bf16 bf16x4 __attribute__((ext_vector_type(4)));
typedef __bf16 bf16x8 __attribute__((ext_vector_type(8)));
typedef float  f32x4  __attribute__((ext_vector_type(4)));

#define BATCH 4
#define SEQ   2048
#define DIM   1024

// RNE float -> bf16
__device__ __forceinline__ bf16 to_bf16(float f) {
    unsigned u = __builtin_bit_cast(unsigned, f);
    u += 0x7fffu + ((u >> 16) & 1u);
    unsigned short h = (unsigned short)(u >> 16);
    return __builtin_bit_cast(bf16, h);
}

// async global->LDS, 16B per lane. LDS dest is wave-uniform base + lane*16.
__device__ __forceinline__ void load16_lds(const bf16* g, bf16* l) {
    __builtin_amdgcn_global_load_lds(
        (__attribute__((address_space(1))) void*)(g),
        (__attribute__((address_space(3))) void*)(l),
        16, 0, 0);
}

// XCD-affinity swizzle: blocks sharing an A-tile (same y,z) map to dispatch
// ids congruent mod 8 -> same XCD (round-robin heuristic; correctness-safe).
// Requires gridDim.y*gridDim.z % 8 == 0.
__device__ __forceinline__ void swizzle_xyz(int& bx, int& by, int& bz) {
    const int nx = gridDim.x, gy = gridDim.y;
    const int d = blockIdx.x + nx * (blockIdx.y + gy * blockIdx.z);
    const int c = d & 7;
    const int j = d >> 3;
    bx = j % nx;
    const int p = c + 8 * (j / nx);
    by = p % gy;
    bz = p / gy;
}

// ---------------------------------------------------------------------------
// Core: C[128x128] block of A(MxK, row-major) @ B^T, B stored (NxK, row-major).
// 256 threads = 4 waves, each wave 64x64 via 4x4 mfma_f32_16x16x32_bf16.
// ---------------------------------------------------------------------------
__device__ __forceinline__ void gemm_bt_core(
    const bf16* __restrict__ Abase, const bf16* __restrict__ Bbase,
    int K, int lda, int ldb, bf16* As, bf16* Bs, f32x4 acc[4][4])
{
    const int tid  = threadIdx.x;
    const int lane = tid & 63;
    const int wave = tid >> 6;
    const int wm   = (wave >> 1) * 64;
    const int wn   = (wave & 1) * 64;
    const int r16  = lane & 15;
    const int q8   = (lane >> 4) * 8;
    const int srow = tid >> 2;
    const int scol = (tid & 3) * 8;
    const int lb   = (tid & 192) * 8;

    for (int k0 = 0; k0 < K; k0 += 32) {
        __syncthreads();
        const bf16* ga = Abase + (size_t)srow * lda + (k0 + scol);
        const bf16* gb = Bbase + (size_t)srow * ldb + (k0 + scol);
        load16_lds(ga,                     As + lb);
        load16_lds(ga + (size_t)64 * lda,  As + 2048 + lb);
        load16_lds(gb,                     Bs + lb);
        load16_lds(gb + (size_t)64 * ldb,  Bs + 2048 + lb);
        __syncthreads();

        bf16x8 af[4], bfr[4];
#pragma unroll
        for (int i = 0; i < 4; ++i)
            af[i] = *(const bf16x8*)(As + (wm + i * 16 + r16) * 32 + q8);
#pragma unroll
        for (int i = 0; i < 4; ++i)
            bfr[i] = *(const bf16x8*)(Bs + (wn + i * 16 + r16) * 32 + q8);
#pragma unroll
        for (int mi = 0; mi < 4; ++mi)
#pragma unroll
            for (int ni = 0; ni < 4; ++ni)
                acc[mi][ni] = __builtin_amdgcn_mfma_f32_16x16x32_bf16(
                    af[mi], bfr[ni], acc[mi][ni], 0, 0, 0);
    }
}

// ---------------------------------------------------------------------------
// GEMM 1: X[8192,1024] x Wt[3072,1024]^T -> Q,K (row-major bf16) and V
// written TRANSPOSED per batch: Vt[b][d][s].
// grid = (24, 64)
// ---------------------------------------------------------------------------
__global__ __launch_bounds__(256) void qkv_gemm(
    const bf16* __restrict__ X, const bf16* __restrict__ Wt,
    bf16* __restrict__ Q, bf16* __restrict__ Kp, bf16* __restrict__ Vt)
{
    __shared__ bf16 As[4096];
    __shared__ bf16 Bs[4096];
    f32x4 acc[4][4] = {};

    int bx, by, bz;
    swizzle_xyz(bx, by, bz);

    const bf16* Ab = X  + (size_t)by * 128 * DIM;
    const bf16* Bb = Wt + (size_t)bx * 128 * DIM;
    gemm_bt_core(Ab, Bb, DIM, DIM, DIM, As, Bs, acc);

    const int lane = threadIdx.x & 63;
    const int wave = threadIdx.x >> 6;
    const int wm = (wave >> 1) * 64, wn = (wave & 1) * 64;
    const int sel = bx >> 3;                                   // 0:Q 1:K 2:V
    const int colBase = (bx & 7) * 128 + wn + (lane & 15);     // 0..1023 in matrix
    const int rowBase = by * 128 + wm + ((lane >> 4) * 4);     // flat m = b*SEQ+s

    if (sel < 2) {
        bf16* dst = sel ? Kp : Q;
#pragma unroll
        for (int mi = 0; mi < 4; ++mi)
#pragma unroll
            for (int ni = 0; ni < 4; ++ni)
#pragma unroll
                for (int r = 0; r < 4; ++r)
                    dst[(size_t)(rowBase + mi * 16 + r) * DIM + colBase + ni * 16] =
                        to_bf16(acc[mi][ni][r]);
    } else {
        // V transposed: Vt[b][d][s], 4 consecutive s per thread -> 8B stores
        const int b = (by * 128) >> 11;                        // batch
        bf16* Vtb = Vt + (size_t)b * DIM * SEQ;
#pragma unroll
        for (int mi = 0; mi < 4; ++mi) {
            const int s0 = (rowBase + mi * 16) & (SEQ - 1);
#pragma unroll
            for (int ni = 0; ni < 4; ++ni) {
                const int d = colBase + ni * 16;
                bf16x4 o = { to_bf16(acc[mi][ni][0]), to_bf16(acc[mi][ni][1]),
                             to_bf16(acc[mi][ni][2]), to_bf16(acc[mi][ni][3]) };
                *(bf16x4*)(Vtb + (size_t)d * SEQ + s0) = o;
            }
        }
    }
}

// ---------------------------------------------------------------------------
// batched bt-GEMM -> bf16 output (scaled). grid = (N/128, M/128, batch)
// ---------------------------------------------------------------------------
__global__ __launch_bounds__(256) void gemm_bt_bf16(
    const bf16* __restrict__ A, const bf16* __restrict__ Bm, bf16* __restrict__ C,
    int K, int lda, int ldb, int ldc, float scale, long strA, long strB, long strC)
{
    __shared__ bf16 As[4096];
    __shared__ bf16 Bs[4096];
    f32x4 acc[4][4] = {};

    int bx, by, bz;
    swizzle_xyz(bx, by, bz);

    const bf16* Ab = A  + (size_t)bz * strA + (size_t)by * 128 * lda;
    const bf16* Bb = Bm + (size_t)bz * strB + (size_t)bx * 128 * ldb;
    bf16* Cb = C + (size_t)bz * strC;
    gemm_bt_core(Ab, Bb, K, lda, ldb, As, Bs, acc);

    const int lane = threadIdx.x & 63;
    const int wave = threadIdx.x >> 6;
    const int wm = (wave >> 1) * 64, wn = (wave & 1) * 64;
    const int rowBase = by * 128 + wm + ((lane >> 4) * 4);
    const int colBase = bx * 128 + wn + (lane & 15);
#pragma unroll
    for (int mi = 0; mi < 4; ++mi)
#pragma unroll
        for (int ni = 0; ni < 4; ++ni)
#pragma unroll
            for (int r = 0; r < 4; ++r)
                Cb[(size_t)(rowBase + mi * 16 + r) * ldc + colBase + ni * 16] =
                    to_bf16(acc[mi][ni][r] * scale);
}

// ---------------------------------------------------------------------------
// batched bt-GEMM -> fp32 output. grid = (N/128, M/128, batch)
// ---------------------------------------------------------------------------
__global__ __launch_bounds__(256) void gemm_bt_f32(
    const bf16* __restrict__ A, const bf16* __restrict__ Bm, float* __restrict__ C,
    int K, int lda, int ldb, int ldc, long strA, long strB, long strC)
{
    __shared__ bf16 As[4096];
    __shared__ bf16 Bs[4096];
    f32x4 acc[4][4] = {};

    int bx, by, bz;
    swizzle_xyz(bx, by, bz);

    const bf16* Ab = A  + (size_t)bz * strA + (size_t)by * 128 * lda;
    const bf16* Bb = Bm + (size_t)bz * strB + (size_t)bx * 128 * ldb;
    float* Cb = C + (size_t)bz * strC;
    gemm_bt_core(Ab, Bb, K, lda, ldb, As, Bs, acc);

    const int lane = threadIdx.x & 63;
    const int wave = threadIdx.x >> 6;
    const int wm = (wave >> 1) * 64, wn = (wave & 1) * 64;
    const int rowBase = by * 128 + wm + ((lane >> 4) * 4);
    const int colBase = bx * 128 + wn + (lane & 15);
#pragma unroll
    for (int mi = 0; mi < 4; ++mi)
#pragma unroll
        for (int ni = 0; ni < 4; ++ni)
#pragma unroll
            for (int r = 0; r < 4; ++r)
                Cb[(size_t)(rowBase + mi * 16 + r) * ldc + colBase + ni * 16] =
                    acc[mi][ni][r];
}

// ---------------------------------------------------------------------------
// fp32 -> bf16 cast (x), vectorized
// ---------------------------------------------------------------------------
__global__ __launch_bounds__(256) void cvt_x(const float* __restrict__ x, bf16* __restrict__ y) {
    const size_t i = ((size_t)blockIdx.x * 256 + threadIdx.x) * 4;
    const float4 v = *(const float4*)(x + i);
    bf16x4 o = { to_bf16(v.x), to_bf16(v.y), to_bf16(v.z), to_bf16(v.w) };
    *(bf16x4*)(y + i) = o;
}

// ---------------------------------------------------------------------------
// weights: [1024,1024] fp32 -> transposed bf16 [3072,1024]
// grid = (32, 32, 3), block = (32, 8)
// ---------------------------------------------------------------------------
__global__ void cvt_w_t(const float* __restrict__ wq, const float* __restrict__ wk,
                        const float* __restrict__ wv, bf16* __restrict__ Wt)
{
    __shared__ float tile[32][33];
    const int sel = blockIdx.z;
    const float* w = (sel == 0) ? wq : (sel == 1) ? wk : wv;
    const int n0 = blockIdx.x * 32;
    const int k0 = blockIdx.y * 32;
    const int tx = threadIdx.x, ty = threadIdx.y;
#pragma unroll
    for (int j = 0; j < 32; j += 8)
        tile[ty + j][tx] = w[(size_t)(k0 + ty + j) * 1024 + n0 + tx];
    __syncthreads();
    bf16* dst = Wt + (size_t)sel * 1024 * 1024;
#pragma unroll
    for (int j = 0; j < 32; j += 8)
        dst[(size_t)(n0 + ty + j) * 1024 + k0 + tx] = to_bf16(tile[tx][ty + j]);
}

// ---------------------------------------------------------------------------
// row softmax over 2048 bf16 scores -> bf16 P. grid = (8192), block = 256
// ---------------------------------------------------------------------------
__global__ __launch_bounds__(256) void softmax_k(const bf16* __restrict__ Sc,
                                                 bf16* __restrict__ P)
{
    __shared__ float red[8];
    const size_t row = blockIdx.x;
    const int tid = threadIdx.x;
    const int lane = tid & 63;
    const int wave = tid >> 6;

    const bf16x8 v = *(const bf16x8*)(Sc + row * (size_t)SEQ + tid * 8);
    float e[8];
#pragma unroll
    for (int i = 0; i < 8; ++i) e[i] = (float)v[i];

    float mx = e[0];
#pragma unroll
    for (int i = 1; i < 8; ++i) mx = fmaxf(mx, e[i]);
#pragma unroll
    for (int off = 32; off >= 1; off >>= 1) mx = fmaxf(mx, __shfl_xor(mx, off));
    if (lane == 0) red[wave] = mx;
    __syncthreads();
    mx = fmaxf(fmaxf(red[0], red[1]), fmaxf(red[2], red[3]));

    float sum = 0.f;
#pragma unroll
    for (int i = 0; i < 8; ++i) { e[i] = __expf(e[i] - mx); sum += e[i]; }
#pragma unroll
    for (int off = 32; off >= 1; off >>= 1) sum += __shfl_xor(sum, off);
    if (lane == 0) red[4 + wave] = sum;
    __syncthreads();
    sum = (red[4] + red[5]) + (red[6] + red[7]);
    const float inv = 1.0f / sum;

    bf16x8 o;
#pragma unroll
    for (int i = 0; i < 8; ++i) o[i] = to_bf16(e[i] * inv);
    *(bf16x8*)(P + row * (size_t)SEQ + tid * 8) = o;
}

// ---------------------------------------------------------------------------
extern "C" void kernel_launch(void* const* d_in, const int* in_sizes, int n_in,
                              void* d_out, int out_size, void* d_ws, size_t ws_size,
                              hipStream_t stream)
{
    const float* x  = (const float*)d_in[0];
    const float* wq = (const float*)d_in[1];
    const float* wk = (const float*)d_in[2];
    const float* wv = (const float*)d_in[3];
    float* out = (float*)d_out;
    char* ws = (char*)d_ws;

    // workspace layout (bytes)
    bf16* xb = (bf16*)(ws);                        // 16 MB [8192,1024]
    bf16* Wt = (bf16*)(ws + (16u << 20));          //  6 MB [3072,1024]
    bf16* Q  = (bf16*)(ws + (22u << 20));          // 16 MB
    bf16* Kp = (bf16*)(ws + (38u << 20));          // 16 MB
    bf16* Vt = (bf16*)(ws + (54u << 20));          // 16 MB [4][1024][2048]
    bf16* Sc = (bf16*)(ws + (70u << 20));          // 32 MB [4,2048,2048] bf16
    bf16* P  = (bf16*)(ws + (102u << 20));         // 32 MB

    cvt_x<<<dim3(8192), dim3(256), 0, stream>>>(x, xb);
    cvt_w_t<<<dim3(32, 32, 3), dim3(32, 8), 0, stream>>>(wq, wk, wv, Wt);

    // QKV projection: M=8192, N=3072, K=1024; V written transposed
    qkv_gemm<<<dim3(24, 64), dim3(256), 0, stream>>>(xb, Wt, Q, Kp, Vt);

    // scores = Q @ K^T * (1/32) -> bf16: per batch M=N=2048, K=1024
    gemm_bt_bf16<<<dim3(16, 16, 4), dim3(256), 0, stream>>>(
        Q, Kp, Sc, 1024, 1024, 1024, 2048, 0.03125f,
        (long)SEQ * DIM, (long)SEQ * DIM, (long)SEQ * SEQ);

    softmax_k<<<dim3(BATCH * SEQ), dim3(256), 0, stream>>>(Sc, P);

    // out = P @ Vt^T: per batch M=2048, N=1024, K=2048
    gemm_bt_f32<<<dim3(8, 16, 4), dim3(256), 0, stream>>>(
        P, Vt, out, 2048, 2048, 2048, 1024,
        (long)SEQ * SEQ, (long)DIM * SEQ, (long)SEQ * DIM);
}

// Round 3
// 290.215 us; speedup vs baseline: 1.0458x; 1.0148x over previous
//
#include <hip/hip_runtime.h>
#include <cstdint>
#include <cstddef>

typedef __bf16 bf16;
typedef __bf16 bf16x4 __attribute__((ext_vector_type(4)));
typedef __bf16 bf16x8 __attribute__((ext_vector_type(8)));
typedef float  f32x4  __attribute__((ext_vector_type(4)));

#define BATCH 4
#define SEQ   2048
#define DIM   1024

// RNE float -> bf16
__device__ __forceinline__ bf16 to_bf16(float f) {
    unsigned u = __builtin_bit_cast(unsigned, f);
    u += 0x7fffu + ((u >> 16) & 1u);
    unsigned short h = (unsigned short)(u >> 16);
    return __builtin_bit_cast(bf16, h);
}

// async global->LDS, 16B per lane. LDS dest is wave-uniform base + lane*16.
__device__ __forceinline__ void load16_lds(const bf16* g, bf16* l) {
    __builtin_amdgcn_global_load_lds(
        (__attribute__((address_space(1))) void*)(g),
        (__attribute__((address_space(3))) void*)(l),
        16, 0, 0);
}

// Compile-time XCD-affinity swizzle (NX, GY powers of 2; GY*GZ % 8 == 0).
// Blocks sharing an A-strip (same by,bz) get dispatch ids congruent mod 8
// -> same XCD under round-robin dispatch. All mod/div fold to masks/shifts.
template<int NX, int GY>
__device__ __forceinline__ void swz(int& bx, int& by, int& bz) {
    const int d = blockIdx.x + NX * (blockIdx.y + GY * blockIdx.z);
    const int c = d & 7;
    const int j = d >> 3;
    bx = j % NX;
    const int p = c + 8 * (j / NX);
    by = p % GY;
    bz = p / GY;
}

// ---------------------------------------------------------------------------
// Core: C[128x128] block of A(MxK, row-major) @ B^T, B stored (NxK, row-major).
// 256 threads = 4 waves, each wave 64x64 via 4x4 mfma_f32_16x16x32_bf16.
// ---------------------------------------------------------------------------
__device__ __forceinline__ void gemm_bt_core(
    const bf16* __restrict__ Abase, const bf16* __restrict__ Bbase,
    int K, int lda, int ldb, bf16* As, bf16* Bs, f32x4 acc[4][4])
{
    const int tid  = threadIdx.x;
    const int lane = tid & 63;
    const int wave = tid >> 6;
    const int wm   = (wave >> 1) * 64;
    const int wn   = (wave & 1) * 64;
    const int r16  = lane & 15;
    const int q8   = (lane >> 4) * 8;
    const int srow = tid >> 2;
    const int scol = (tid & 3) * 8;
    const int lb   = (tid & 192) * 8;

    for (int k0 = 0; k0 < K; k0 += 32) {
        __syncthreads();
        const bf16* ga = Abase + (size_t)srow * lda + (k0 + scol);
        const bf16* gb = Bbase + (size_t)srow * ldb + (k0 + scol);
        load16_lds(ga,                     As + lb);
        load16_lds(ga + (size_t)64 * lda,  As + 2048 + lb);
        load16_lds(gb,                     Bs + lb);
        load16_lds(gb + (size_t)64 * ldb,  Bs + 2048 + lb);
        __syncthreads();

        bf16x8 af[4], bfr[4];
#pragma unroll
        for (int i = 0; i < 4; ++i)
            af[i] = *(const bf16x8*)(As + (wm + i * 16 + r16) * 32 + q8);
#pragma unroll
        for (int i = 0; i < 4; ++i)
            bfr[i] = *(const bf16x8*)(Bs + (wn + i * 16 + r16) * 32 + q8);
#pragma unroll
        for (int mi = 0; mi < 4; ++mi)
#pragma unroll
            for (int ni = 0; ni < 4; ++ni)
                acc[mi][ni] = __builtin_amdgcn_mfma_f32_16x16x32_bf16(
                    af[mi], bfr[ni], acc[mi][ni], 0, 0, 0);
    }
}

// ---------------------------------------------------------------------------
// Plain bt-GEMM -> bf16 C (row-major coalesced). Used for QK and Vt.
// grid = (NX, GY, GZ)
// ---------------------------------------------------------------------------
template<int NX, int GY>
__global__ __launch_bounds__(256) void gemm_bt_bf16(
    const bf16* __restrict__ A, const bf16* __restrict__ Bm, bf16* __restrict__ C,
    int K, int lda, int ldb, int ldc, long strA, long strB, long strC)
{
    __shared__ bf16 As[4096];
    __shared__ bf16 Bs[4096];
    f32x4 acc[4][4] = {};

    int bx, by, bz;
    swz<NX, GY>(bx, by, bz);

    const bf16* Ab = A  + (size_t)bz * strA + (size_t)by * 128 * lda;
    const bf16* Bb = Bm + (size_t)bz * strB + (size_t)bx * 128 * ldb;
    bf16* Cb = C + (size_t)bz * strC;
    gemm_bt_core(Ab, Bb, K, lda, ldb, As, Bs, acc);

    const int lane = threadIdx.x & 63;
    const int wave = threadIdx.x >> 6;
    const int wm = (wave >> 1) * 64, wn = (wave & 1) * 64;
    const int rowBase = by * 128 + wm + ((lane >> 4) * 4);
    const int colBase = bx * 128 + wn + (lane & 15);
#pragma unroll
    for (int mi = 0; mi < 4; ++mi)
#pragma unroll
        for (int ni = 0; ni < 4; ++ni)
#pragma unroll
            for (int r = 0; r < 4; ++r)
                Cb[(size_t)(rowBase + mi * 16 + r) * ldc + colBase + ni * 16] =
                    to_bf16(acc[mi][ni][r]);
}

// ---------------------------------------------------------------------------
// scores GEMM: S = Q @ K^T * scale; epilogue stores P' = exp(S) (bf16, no
// max-sub: |S| <~ 6) and atomically accumulates fp32 row sums into lsum.
// grid = (16, 16, 4)
// ---------------------------------------------------------------------------
__global__ __launch_bounds__(256) void gemm_scores(
    const bf16* __restrict__ A, const bf16* __restrict__ Bm, bf16* __restrict__ C,
    float* __restrict__ lsum)
{
    __shared__ bf16 As[4096];
    __shared__ bf16 Bs[4096];
    f32x4 acc[4][4] = {};

    int bx, by, bz;
    swz<16, 16>(bx, by, bz);

    const int lda = 2 * DIM;                  // QK fused buffer
    const bf16* Ab = A  + (size_t)bz * SEQ * lda + (size_t)by * 128 * lda;
    const bf16* Bb = Bm + (size_t)bz * SEQ * lda + (size_t)bx * 128 * lda;
    bf16* Cb = C + (size_t)bz * SEQ * SEQ;
    gemm_bt_core(Ab, Bb, DIM, lda, lda, As, Bs, acc);

    const int lane = threadIdx.x & 63;
    const int wave = threadIdx.x >> 6;
    const int wm = (wave >> 1) * 64, wn = (wave & 1) * 64;
    const int rowBase = by * 128 + wm + ((lane >> 4) * 4);
    const int colBase = bx * 128 + wn + (lane & 15);

    // exp in place, store P'
#pragma unroll
    for (int mi = 0; mi < 4; ++mi)
#pragma unroll
        for (int ni = 0; ni < 4; ++ni)
#pragma unroll
            for (int r = 0; r < 4; ++r) {
                const float e = __expf(acc[mi][ni][r] * 0.03125f);
                acc[mi][ni][r] = e;
                Cb[(size_t)(rowBase + mi * 16 + r) * SEQ + colBase + ni * 16] =
                    to_bf16(e);
            }

    // per-row partial sums over this wave's 64 cols -> atomic into lsum
    float* ls = lsum + (size_t)bz * SEQ;
#pragma unroll
    for (int mi = 0; mi < 4; ++mi)
#pragma unroll
        for (int r = 0; r < 4; ++r) {
            float s = acc[mi][0][r] + acc[mi][1][r] + acc[mi][2][r] + acc[mi][3][r];
            s += __shfl_xor(s, 1);
            s += __shfl_xor(s, 2);
            s += __shfl_xor(s, 4);
            s += __shfl_xor(s, 8);
            if ((lane & 15) == 0)
                atomicAdd(ls + rowBase + mi * 16 + r, s);
        }
}

// ---------------------------------------------------------------------------
// PV GEMM: out = (P' @ Vt^T) / l, fp32 out. grid = (8, 16, 4)
// ---------------------------------------------------------------------------
__global__ __launch_bounds__(256) void gemm_pv(
    const bf16* __restrict__ A, const bf16* __restrict__ Bm, float* __restrict__ C,
    const float* __restrict__ lsum)
{
    __shared__ bf16 As[4096];
    __shared__ bf16 Bs[4096];
    f32x4 acc[4][4] = {};

    int bx, by, bz;
    swz<8, 16>(bx, by, bz);

    const bf16* Ab = A  + (size_t)bz * SEQ * SEQ + (size_t)by * 128 * SEQ;
    const bf16* Bb = Bm + (size_t)bz * DIM * SEQ + (size_t)bx * 128 * SEQ;
    float* Cb = C + (size_t)bz * SEQ * DIM;
    gemm_bt_core(Ab, Bb, SEQ, SEQ, SEQ, As, Bs, acc);

    const int lane = threadIdx.x & 63;
    const int wave = threadIdx.x >> 6;
    const int wm = (wave >> 1) * 64, wn = (wave & 1) * 64;
    const int rowBase = by * 128 + wm + ((lane >> 4) * 4);
    const int colBase = bx * 128 + wn + (lane & 15);
    const float* ls = lsum + (size_t)bz * SEQ;
#pragma unroll
    for (int mi = 0; mi < 4; ++mi)
#pragma unroll
        for (int r = 0; r < 4; ++r) {
            const float inv = __builtin_amdgcn_rcpf(ls[rowBase + mi * 16 + r]);
#pragma unroll
            for (int ni = 0; ni < 4; ++ni)
                Cb[(size_t)(rowBase + mi * 16 + r) * DIM + colBase + ni * 16] =
                    acc[mi][ni][r] * inv;
        }
}

// ---------------------------------------------------------------------------
// fp32 -> bf16 cast (x), vectorized
// ---------------------------------------------------------------------------
__global__ __launch_bounds__(256) void cvt_x(const float* __restrict__ x, bf16* __restrict__ y) {
    const size_t i = ((size_t)blockIdx.x * 256 + threadIdx.x) * 4;
    const float4 v = *(const float4*)(x + i);
    bf16x4 o = { to_bf16(v.x), to_bf16(v.y), to_bf16(v.z), to_bf16(v.w) };
    *(bf16x4*)(y + i) = o;
}

// ---------------------------------------------------------------------------
// weights: [1024,1024] fp32 -> transposed bf16 [3072,1024]
// grid = (32, 32, 3), block = (32, 8)
// ---------------------------------------------------------------------------
__global__ void cvt_w_t(const float* __restrict__ wq, const float* __restrict__ wk,
                        const float* __restrict__ wv, bf16* __restrict__ Wt)
{
    __shared__ float tile[32][33];
    const int sel = blockIdx.z;
    const float* w = (sel == 0) ? wq : (sel == 1) ? wk : wv;
    const int n0 = blockIdx.x * 32;
    const int k0 = blockIdx.y * 32;
    const int tx = threadIdx.x, ty = threadIdx.y;
#pragma unroll
    for (int j = 0; j < 32; j += 8)
        tile[ty + j][tx] = w[(size_t)(k0 + ty + j) * 1024 + n0 + tx];
    __syncthreads();
    bf16* dst = Wt + (size_t)sel * 1024 * 1024;
#pragma unroll
    for (int j = 0; j < 32; j += 8)
        dst[(size_t)(n0 + ty + j) * 1024 + k0 + tx] = to_bf16(tile[tx][ty + j]);
}

// ---------------------------------------------------------------------------
extern "C" void kernel_launch(void* const* d_in, const int* in_sizes, int n_in,
                              void* d_out, int out_size, void* d_ws, size_t ws_size,
                              hipStream_t stream)
{
    const float* x  = (const float*)d_in[0];
    const float* wq = (const float*)d_in[1];
    const float* wk = (const float*)d_in[2];
    const float* wv = (const float*)d_in[3];
    float* out = (float*)d_out;
    char* ws = (char*)d_ws;

    // workspace layout (bytes)
    bf16*  xb   = (bf16*)(ws);                   // 16 MB [8192,1024]
    bf16*  Wt   = (bf16*)(ws + (16u << 20));     //  6 MB [3072,1024] (WqT|WkT|WvT)
    bf16*  QK   = (bf16*)(ws + (22u << 20));     // 32 MB [8192,2048] (Q cols 0-1023, K 1024-2047)
    bf16*  Vt   = (bf16*)(ws + (54u << 20));     // 16 MB [4][1024][2048]
    bf16*  P    = (bf16*)(ws + (70u << 20));     // 32 MB [4,2048,2048] unnormalized exp(S)
    float* lsum = (float*)(ws + (102u << 20));   // 32 KB [8192] row sums

    hipMemsetAsync(lsum, 0, BATCH * SEQ * sizeof(float), stream);
    cvt_x<<<dim3(8192), dim3(256), 0, stream>>>(x, xb);
    cvt_w_t<<<dim3(32, 32, 3), dim3(32, 8), 0, stream>>>(wq, wk, wv, Wt);

    // QK: [8192,1024] x WqkT[2048,1024]^T -> QK[8192,2048]
    gemm_bt_bf16<16, 64><<<dim3(16, 64, 1), dim3(256), 0, stream>>>(
        xb, Wt, QK, DIM, DIM, DIM, 2 * DIM, 0, 0, 0);

    // Vt: per batch, WvT[1024,1024] x X[2048,1024]^T -> Vt[b][1024][2048]
    gemm_bt_bf16<16, 8><<<dim3(16, 8, 4), dim3(256), 0, stream>>>(
        Wt + (size_t)2 * DIM * DIM, xb, Vt, DIM, DIM, DIM, SEQ,
        0, (long)SEQ * DIM, (long)DIM * SEQ);

    // P' = exp(Q @ K^T / 32), row sums -> lsum
    gemm_scores<<<dim3(16, 16, 4), dim3(256), 0, stream>>>(QK, QK + DIM, P, lsum);

    // out = (P' @ Vt^T) / l
    gemm_pv<<<dim3(8, 16, 4), dim3(256), 0, stream>>>(P, Vt, out, lsum);
}

// Round 4
// 240.781 us; speedup vs baseline: 1.2605x; 1.2053x over previous
//
#include <hip/hip_runtime.h>
#include <cstdint>
#include <cstddef>

typedef __bf16 bf16;
typedef __bf16 bf16x4 __attribute__((ext_vector_type(4)));
typedef __bf16 bf16x8 __attribute__((ext_vector_type(8)));
typedef float  f32x4  __attribute__((ext_vector_type(4)));

#define BATCH 4
#define SEQ   2048
#define DIM   1024

// RNE float -> bf16
__device__ __forceinline__ bf16 to_bf16(float f) {
    unsigned u = __builtin_bit_cast(unsigned, f);
    u += 0x7fffu + ((u >> 16) & 1u);
    unsigned short h = (unsigned short)(u >> 16);
    return __builtin_bit_cast(bf16, h);
}

// async global->LDS, 16B per lane. LDS base must be wave-uniform; HW adds lane*16.
__device__ __forceinline__ void load16_lds(const bf16* g, bf16* l) {
    __builtin_amdgcn_global_load_lds(
        (__attribute__((address_space(1))) void*)(g),
        (__attribute__((address_space(3))) void*)(l),
        16, 0, 0);
}

// ---------------------------------------------------------------------------
// BK=64 core with XOR-swizzled LDS chunk layout.
// Tile: C 128x128, A/B staged as [128 rows][8 chunks of 8 bf16]. Physical
// chunk p = logical c ^ (row & 7) -> fragment reads are 2-way-max on banks.
// Staging: 4 issues x 256 lanes x 16B per matrix; LDS dest contiguous per
// wave (lane*16), global side supplies the swizzle via per-lane addresses.
// ---------------------------------------------------------------------------
__device__ __forceinline__ void gemm_core64(
    const bf16* __restrict__ Abase, const bf16* __restrict__ Bbase,
    int K, int lda, int ldb, bf16* As, bf16* Bs, f32x4 acc[4][4])
{
    const int tid  = threadIdx.x;
    const int lane = tid & 63;
    const int wave = tid >> 6;
    const int wm   = (wave >> 1) * 64;
    const int wn   = (wave & 1) * 64;
    const int r16  = lane & 15;
    const int g    = lane >> 4;                        // fragment k-chunk group 0..3
    const int srow0 = wave * 8 + (lane >> 3);          // staging row 0..31 per issue
    const int scoff = (((lane & 7) ^ ((lane >> 3) & 7)) * 8); // logical k-chunk elems
    const int ldsW  = wave * 512;                      // elements

    for (int k0 = 0; k0 < K; k0 += 64) {
        __syncthreads();
#pragma unroll
        for (int j = 0; j < 4; ++j) {
            load16_lds(Abase + (size_t)(j * 32 + srow0) * lda + k0 + scoff,
                       As + j * 2048 + ldsW);
            load16_lds(Bbase + (size_t)(j * 32 + srow0) * ldb + k0 + scoff,
                       Bs + j * 2048 + ldsW);
        }
        __syncthreads();

#pragma unroll
        for (int h = 0; h < 2; ++h) {
            bf16x8 af[4], bfr[4];
            const int pc = h * 4 + g;                  // logical chunk
#pragma unroll
            for (int i = 0; i < 4; ++i) {
                const int p = pc ^ (r16 & 7);
                af[i]  = *(const bf16x8*)(As + (wm + i * 16 + r16) * 64 + p * 8);
                bfr[i] = *(const bf16x8*)(Bs + (wn + i * 16 + r16) * 64 + p * 8);
            }
#pragma unroll
            for (int mi = 0; mi < 4; ++mi)
#pragma unroll
                for (int ni = 0; ni < 4; ++ni)
                    acc[mi][ni] = __builtin_amdgcn_mfma_f32_16x16x32_bf16(
                        af[mi], bfr[ni], acc[mi][ni], 0, 0, 0);
        }
    }
}

// ---------------------------------------------------------------------------
// Merged projection GEMM: blocks [0,1024) compute QK = X @ WqkT^T
// ([8192,2048]); blocks [1024,1536) compute Vt[b] = WvT @ X[b]^T
// ([1024,2048] per batch). Both epilogues: bf16 row-major, ldc=2048.
// XCD swizzle: same-A-strip blocks get raw ids congruent mod 8.
// ---------------------------------------------------------------------------
__global__ __launch_bounds__(256, 4) void proj_gemm(
    const bf16* __restrict__ xb, const bf16* __restrict__ Wt,
    bf16* __restrict__ QK, bf16* __restrict__ Vt)
{
    __shared__ bf16 As[8192];
    __shared__ bf16 Bs[8192];
    f32x4 acc[4][4] = {};

    const int r = blockIdx.x;
    const bf16 *Ab, *Bb;
    bf16* Cb;
    int bx, byl;
    if (r < 1024) {                       // QK part
        const int c = r & 7, j = r >> 3;  // j 0..127
        bx  = j & 15;
        byl = c + 8 * (j >> 4);           // 0..63
        Ab = xb + (size_t)byl * 128 * DIM;
        Bb = Wt + (size_t)bx * 128 * DIM;
        Cb = QK + (size_t)byl * 128 * 2048;
    } else {                              // Vt part
        const int u = r - 1024;
        const int c = u & 7, j = u >> 3;  // j 0..63
        bx = j & 15;
        const int p = c + 8 * (j >> 4);   // 0..31
        byl = p & 7;                      // M-tile of WvT (1024 rows -> 8)
        const int bz = p >> 3;            // batch
        Ab = Wt + (size_t)2 * DIM * DIM + (size_t)byl * 128 * DIM;
        Bb = xb + (size_t)bz * SEQ * DIM + (size_t)bx * 128 * DIM;
        Cb = Vt + (size_t)bz * DIM * SEQ + (size_t)byl * 128 * 2048;
    }
    gemm_core64(Ab, Bb, DIM, DIM, DIM, As, Bs, acc);

    const int lane = threadIdx.x & 63;
    const int wave = threadIdx.x >> 6;
    const int wm = (wave >> 1) * 64, wn = (wave & 1) * 64;
    const int rowO = wm + ((lane >> 4) * 4);
    const int colO = bx * 128 + wn + (lane & 15);
#pragma unroll
    for (int mi = 0; mi < 4; ++mi)
#pragma unroll
        for (int ni = 0; ni < 4; ++ni)
#pragma unroll
            for (int rr = 0; rr < 4; ++rr)
                Cb[(size_t)(rowO + mi * 16 + rr) * 2048 + colO + ni * 16] =
                    to_bf16(acc[mi][ni][rr]);
}

// ---------------------------------------------------------------------------
// scores GEMM: P' = exp((Q @ K^T)/32) (bf16), fp32 row sums via atomics.
// grid = (16, 16, 4)
// ---------------------------------------------------------------------------
__global__ __launch_bounds__(256, 4) void gemm_scores(
    const bf16* __restrict__ A, const bf16* __restrict__ Bm, bf16* __restrict__ C,
    float* __restrict__ lsum)
{
    __shared__ bf16 As[8192];
    __shared__ bf16 Bs[8192];
    f32x4 acc[4][4] = {};

    // swizzle: same by,bz -> same XCD
    const int d = blockIdx.x + 16 * (blockIdx.y + 16 * blockIdx.z);
    const int c = d & 7, j = d >> 3;
    const int bx = j & 15;
    const int p = c + 8 * (j >> 4);
    const int by = p & 15, bz = p >> 4;

    const int lda = 2 * DIM;
    const bf16* Ab = A  + (size_t)bz * SEQ * lda + (size_t)by * 128 * lda;
    const bf16* Bb = Bm + (size_t)bz * SEQ * lda + (size_t)bx * 128 * lda;
    bf16* Cb = C + (size_t)bz * SEQ * SEQ;
    gemm_core64(Ab, Bb, DIM, lda, lda, As, Bs, acc);

    const int lane = threadIdx.x & 63;
    const int wave = threadIdx.x >> 6;
    const int wm = (wave >> 1) * 64, wn = (wave & 1) * 64;
    const int rowBase = by * 128 + wm + ((lane >> 4) * 4);
    const int colBase = bx * 128 + wn + (lane & 15);

#pragma unroll
    for (int mi = 0; mi < 4; ++mi)
#pragma unroll
        for (int ni = 0; ni < 4; ++ni)
#pragma unroll
            for (int rr = 0; rr < 4; ++rr) {
                const float e = __expf(acc[mi][ni][rr] * 0.03125f);
                acc[mi][ni][rr] = e;
                Cb[(size_t)(rowBase + mi * 16 + rr) * SEQ + colBase + ni * 16] =
                    to_bf16(e);
            }

    float* ls = lsum + (size_t)bz * SEQ;
#pragma unroll
    for (int mi = 0; mi < 4; ++mi)
#pragma unroll
        for (int rr = 0; rr < 4; ++rr) {
            float s = acc[mi][0][rr] + acc[mi][1][rr] + acc[mi][2][rr] + acc[mi][3][rr];
            s += __shfl_xor(s, 1);
            s += __shfl_xor(s, 2);
            s += __shfl_xor(s, 4);
            s += __shfl_xor(s, 8);
            if ((lane & 15) == 0)
                atomicAdd(ls + rowBase + mi * 16 + rr, s);
        }
}

// ---------------------------------------------------------------------------
// PV GEMM: out = (P' @ Vt^T) / l, fp32. grid = (8, 16, 4)
// ---------------------------------------------------------------------------
__global__ __launch_bounds__(256, 4) void gemm_pv(
    const bf16* __restrict__ A, const bf16* __restrict__ Bm, float* __restrict__ C,
    const float* __restrict__ lsum)
{
    __shared__ bf16 As[8192];
    __shared__ bf16 Bs[8192];
    f32x4 acc[4][4] = {};

    const int d = blockIdx.x + 8 * (blockIdx.y + 16 * blockIdx.z);
    const int c = d & 7, j = d >> 3;
    const int bx = j & 7;
    const int p = c + 8 * (j >> 3);
    const int by = p & 15, bz = p >> 4;

    const bf16* Ab = A  + (size_t)bz * SEQ * SEQ + (size_t)by * 128 * SEQ;
    const bf16* Bb = Bm + (size_t)bz * DIM * SEQ + (size_t)bx * 128 * SEQ;
    float* Cb = C + (size_t)bz * SEQ * DIM;
    gemm_core64(Ab, Bb, SEQ, SEQ, SEQ, As, Bs, acc);

    const int lane = threadIdx.x & 63;
    const int wave = threadIdx.x >> 6;
    const int wm = (wave >> 1) * 64, wn = (wave & 1) * 64;
    const int rowBase = by * 128 + wm + ((lane >> 4) * 4);
    const int colBase = bx * 128 + wn + (lane & 15);
    const float* ls = lsum + (size_t)bz * SEQ;
#pragma unroll
    for (int mi = 0; mi < 4; ++mi)
#pragma unroll
        for (int rr = 0; rr < 4; ++rr) {
            const float inv = __builtin_amdgcn_rcpf(ls[rowBase + mi * 16 + rr]);
#pragma unroll
            for (int ni = 0; ni < 4; ++ni)
                Cb[(size_t)(rowBase + mi * 16 + rr) * DIM + colBase + ni * 16] =
                    acc[mi][ni][rr] * inv;
        }
}

// ---------------------------------------------------------------------------
// fp32 -> bf16 cast (x)
// ---------------------------------------------------------------------------
__global__ __launch_bounds__(256) void cvt_x(const float* __restrict__ x, bf16* __restrict__ y) {
    const size_t i = ((size_t)blockIdx.x * 256 + threadIdx.x) * 4;
    const float4 v = *(const float4*)(x + i);
    bf16x4 o = { to_bf16(v.x), to_bf16(v.y), to_bf16(v.z), to_bf16(v.w) };
    *(bf16x4*)(y + i) = o;
}

// ---------------------------------------------------------------------------
// weights: [1024,1024] fp32 -> transposed bf16 [3072,1024]
// grid = (32, 32, 3), block = (32, 8)
// ---------------------------------------------------------------------------
__global__ void cvt_w_t(const float* __restrict__ wq, const float* __restrict__ wk,
                        const float* __restrict__ wv, bf16* __restrict__ Wt)
{
    __shared__ float tile[32][33];
    const int sel = blockIdx.z;
    const float* w = (sel == 0) ? wq : (sel == 1) ? wk : wv;
    const int n0 = blockIdx.x * 32;
    const int k0 = blockIdx.y * 32;
    const int tx = threadIdx.x, ty = threadIdx.y;
#pragma unroll
    for (int j = 0; j < 32; j += 8)
        tile[ty + j][tx] = w[(size_t)(k0 + ty + j) * 1024 + n0 + tx];
    __syncthreads();
    bf16* dst = Wt + (size_t)sel * 1024 * 1024;
#pragma unroll
    for (int j = 0; j < 32; j += 8)
        dst[(size_t)(n0 + ty + j) * 1024 + k0 + tx] = to_bf16(tile[tx][ty + j]);
}

// ---------------------------------------------------------------------------
extern "C" void kernel_launch(void* const* d_in, const int* in_sizes, int n_in,
                              void* d_out, int out_size, void* d_ws, size_t ws_size,
                              hipStream_t stream)
{
    const float* x  = (const float*)d_in[0];
    const float* wq = (const float*)d_in[1];
    const float* wk = (const float*)d_in[2];
    const float* wv = (const float*)d_in[3];
    float* out = (float*)d_out;
    char* ws = (char*)d_ws;

    // workspace layout (bytes)
    bf16*  xb   = (bf16*)(ws);                   // 16 MB [8192,1024]
    bf16*  Wt   = (bf16*)(ws + (16u << 20));     //  6 MB [3072,1024] (WqT|WkT|WvT)
    bf16*  QK   = (bf16*)(ws + (22u << 20));     // 32 MB [8192,2048]
    bf16*  Vt   = (bf16*)(ws + (54u << 20));     // 16 MB [4][1024][2048]
    bf16*  P    = (bf16*)(ws + (70u << 20));     // 32 MB [4,2048,2048]
    float* lsum = (float*)(ws + (102u << 20));   // 32 KB [8192]

    hipMemsetAsync(lsum, 0, BATCH * SEQ * sizeof(float), stream);
    cvt_x<<<dim3(8192), dim3(256), 0, stream>>>(x, xb);
    cvt_w_t<<<dim3(32, 32, 3), dim3(32, 8), 0, stream>>>(wq, wk, wv, Wt);

    // QK + Vt in one dispatch
    proj_gemm<<<dim3(1536), dim3(256), 0, stream>>>(xb, Wt, QK, Vt);

    // P' = exp(Q @ K^T / 32), row sums -> lsum
    gemm_scores<<<dim3(16, 16, 4), dim3(256), 0, stream>>>(QK, QK + DIM, P, lsum);

    // out = (P' @ Vt^T) / l
    gemm_pv<<<dim3(8, 16, 4), dim3(256), 0, stream>>>(P, Vt, out, lsum);
}

// Round 5
// 237.434 us; speedup vs baseline: 1.2783x; 1.0141x over previous
//
#include <hip/hip_runtime.h>
#include <cstdint>
#include <cstddef>

typedef __bf16 bf16;
typedef __bf16 bf16x4 __attribute__((ext_vector_type(4)));
typedef __bf16 bf16x8 __attribute__((ext_vector_type(8)));
typedef float  f32x4  __attribute__((ext_vector_type(4)));

#define BATCH 4
#define SEQ   2048
#define DIM   1024

// RNE float -> bf16
__device__ __forceinline__ bf16 to_bf16(float f) {
    unsigned u = __builtin_bit_cast(unsigned, f);
    u += 0x7fffu + ((u >> 16) & 1u);
    unsigned short h = (unsigned short)(u >> 16);
    return __builtin_bit_cast(bf16, h);
}

// async global->LDS, 16B per lane. LDS base must be wave-uniform; HW adds lane*16.
__device__ __forceinline__ void load16_lds(const bf16* g, bf16* l) {
    __builtin_amdgcn_global_load_lds(
        (__attribute__((address_space(1))) void*)(g),
        (__attribute__((address_space(3))) void*)(l),
        16, 0, 0);
}

// ---------------------------------------------------------------------------
// BK=64 core, XOR-swizzled LDS chunk layout (physical chunk = logical ^ (row&7)
// -> 2-way-max bank aliasing, measured 0 conflicts). BM = 64 or 128, BN = 128.
// BM=128: 4 waves as 2x2, wave-tile 64x64, acc[4][4].
// BM=64 : 4 waves as 2x2, wave-tile 32x64, acc[2][4].
// ---------------------------------------------------------------------------
template<int BM>
__device__ __forceinline__ void gemm_core64(
    const bf16* __restrict__ Abase, const bf16* __restrict__ Bbase,
    int K, int lda, int ldb, bf16* As, bf16* Bs, f32x4 acc[BM / 32][4])
{
    constexpr int MI = BM / 32;
    const int tid  = threadIdx.x;
    const int lane = tid & 63;
    const int wave = tid >> 6;
    const int wm   = (wave >> 1) * (BM / 2);
    const int wn   = (wave & 1) * 64;
    const int r16  = lane & 15;
    const int g    = lane >> 4;                        // fragment k-chunk group
    const int srow0 = wave * 8 + (lane >> 3);          // staging row within issue
    const int scoff = (((lane & 7) ^ ((lane >> 3) & 7)) * 8);
    const int ldsW  = wave * 512;

    for (int k0 = 0; k0 < K; k0 += 64) {
        __syncthreads();
#pragma unroll
        for (int j = 0; j < BM / 32; ++j)
            load16_lds(Abase + (size_t)(j * 32 + srow0) * lda + k0 + scoff,
                       As + j * 2048 + ldsW);
#pragma unroll
        for (int j = 0; j < 4; ++j)
            load16_lds(Bbase + (size_t)(j * 32 + srow0) * ldb + k0 + scoff,
                       Bs + j * 2048 + ldsW);
        __syncthreads();

#pragma unroll
        for (int h = 0; h < 2; ++h) {
            bf16x8 af[MI], bfr[4];
            const int p = (h * 4 + g) ^ (r16 & 7);
#pragma unroll
            for (int i = 0; i < MI; ++i)
                af[i]  = *(const bf16x8*)(As + (wm + i * 16 + r16) * 64 + p * 8);
#pragma unroll
            for (int i = 0; i < 4; ++i)
                bfr[i] = *(const bf16x8*)(Bs + (wn + i * 16 + r16) * 64 + p * 8);
#pragma unroll
            for (int mi = 0; mi < MI; ++mi)
#pragma unroll
                for (int ni = 0; ni < 4; ++ni)
                    acc[mi][ni] = __builtin_amdgcn_mfma_f32_16x16x32_bf16(
                        af[mi], bfr[ni], acc[mi][ni], 0, 0, 0);
        }
    }
}

// ---------------------------------------------------------------------------
// Merged projection GEMM (BM=128): blocks [0,1024) -> QK = X @ WqkT^T
// ([8192,2048]); blocks [1024,1536) -> Vt[b] = WvT @ X[b]^T ([1024,2048]/batch).
// ---------------------------------------------------------------------------
__global__ __launch_bounds__(256, 4) void proj_gemm(
    const bf16* __restrict__ xb, const bf16* __restrict__ Wt,
    bf16* __restrict__ QK, bf16* __restrict__ Vt)
{
    __shared__ bf16 As[8192];
    __shared__ bf16 Bs[8192];
    f32x4 acc[4][4] = {};

    const int r = blockIdx.x;
    const bf16 *Ab, *Bb;
    bf16* Cb;
    int bx, byl;
    if (r < 1024) {                       // QK part
        const int c = r & 7, j = r >> 3;
        bx  = j & 15;
        byl = c + 8 * (j >> 4);
        Ab = xb + (size_t)byl * 128 * DIM;
        Bb = Wt + (size_t)bx * 128 * DIM;
        Cb = QK + (size_t)byl * 128 * 2048;
    } else {                              // Vt part
        const int u = r - 1024;
        const int c = u & 7, j = u >> 3;
        bx = j & 15;
        const int p = c + 8 * (j >> 4);
        byl = p & 7;
        const int bz = p >> 3;
        Ab = Wt + (size_t)2 * DIM * DIM + (size_t)byl * 128 * DIM;
        Bb = xb + (size_t)bz * SEQ * DIM + (size_t)bx * 128 * DIM;
        Cb = Vt + (size_t)bz * DIM * SEQ + (size_t)byl * 128 * 2048;
    }
    gemm_core64<128>(Ab, Bb, DIM, DIM, DIM, As, Bs, acc);

    const int lane = threadIdx.x & 63;
    const int wave = threadIdx.x >> 6;
    const int wm = (wave >> 1) * 64, wn = (wave & 1) * 64;
    const int rowO = wm + ((lane >> 4) * 4);
    const int colO = bx * 128 + wn + (lane & 15);
#pragma unroll
    for (int mi = 0; mi < 4; ++mi)
#pragma unroll
        for (int ni = 0; ni < 4; ++ni)
#pragma unroll
            for (int rr = 0; rr < 4; ++rr)
                Cb[(size_t)(rowO + mi * 16 + rr) * 2048 + colO + ni * 16] =
                    to_bf16(acc[mi][ni][rr]);
}

// ---------------------------------------------------------------------------
// scores GEMM (BM=128): P' = exp((Q @ K^T)/32) (bf16), fp32 row sums via
// atomics. grid = (16, 16, 4)
// ---------------------------------------------------------------------------
__global__ __launch_bounds__(256, 4) void gemm_scores(
    const bf16* __restrict__ A, const bf16* __restrict__ Bm, bf16* __restrict__ C,
    float* __restrict__ lsum)
{
    __shared__ bf16 As[8192];
    __shared__ bf16 Bs[8192];
    f32x4 acc[4][4] = {};

    const int d = blockIdx.x + 16 * (blockIdx.y + 16 * blockIdx.z);
    const int c = d & 7, j = d >> 3;
    const int bx = j & 15;
    const int p = c + 8 * (j >> 4);
    const int by = p & 15, bz = p >> 4;

    const int lda = 2 * DIM;
    const bf16* Ab = A  + (size_t)bz * SEQ * lda + (size_t)by * 128 * lda;
    const bf16* Bb = Bm + (size_t)bz * SEQ * lda + (size_t)bx * 128 * lda;
    bf16* Cb = C + (size_t)bz * SEQ * SEQ;
    gemm_core64<128>(Ab, Bb, DIM, lda, lda, As, Bs, acc);

    const int lane = threadIdx.x & 63;
    const int wave = threadIdx.x >> 6;
    const int wm = (wave >> 1) * 64, wn = (wave & 1) * 64;
    const int rowBase = by * 128 + wm + ((lane >> 4) * 4);
    const int colBase = bx * 128 + wn + (lane & 15);

#pragma unroll
    for (int mi = 0; mi < 4; ++mi)
#pragma unroll
        for (int ni = 0; ni < 4; ++ni)
#pragma unroll
            for (int rr = 0; rr < 4; ++rr) {
                const float e = __expf(acc[mi][ni][rr] * 0.03125f);
                acc[mi][ni][rr] = e;
                Cb[(size_t)(rowBase + mi * 16 + rr) * SEQ + colBase + ni * 16] =
                    to_bf16(e);
            }

    float* ls = lsum + (size_t)bz * SEQ;
#pragma unroll
    for (int mi = 0; mi < 4; ++mi)
#pragma unroll
        for (int rr = 0; rr < 4; ++rr) {
            float s = acc[mi][0][rr] + acc[mi][1][rr] + acc[mi][2][rr] + acc[mi][3][rr];
            s += __shfl_xor(s, 1);
            s += __shfl_xor(s, 2);
            s += __shfl_xor(s, 4);
            s += __shfl_xor(s, 8);
            if ((lane & 15) == 0)
                atomicAdd(ls + rowBase + mi * 16 + rr, s);
        }
}

// ---------------------------------------------------------------------------
// PV GEMM (BM=64): out = (P' @ Vt^T) / l, fp32. grid = (8, 32, 4) = 1024
// blocks -> 4 blocks/CU residency (R4's 512-block grid was 2/CU, starved).
// ---------------------------------------------------------------------------
__global__ __launch_bounds__(256, 4) void gemm_pv(
    const bf16* __restrict__ A, const bf16* __restrict__ Bm, float* __restrict__ C,
    const float* __restrict__ lsum)
{
    __shared__ bf16 As[4096];
    __shared__ bf16 Bs[8192];
    f32x4 acc[2][4] = {};

    const int d = blockIdx.x + 8 * (blockIdx.y + 32 * blockIdx.z);
    const int c = d & 7, j = d >> 3;
    const int bx = j & 7;
    const int p = c + 8 * (j >> 3);
    const int by = p & 31, bz = p >> 5;

    const bf16* Ab = A  + (size_t)bz * SEQ * SEQ + (size_t)by * 64 * SEQ;
    const bf16* Bb = Bm + (size_t)bz * DIM * SEQ + (size_t)bx * 128 * SEQ;
    float* Cb = C + (size_t)bz * SEQ * DIM;
    gemm_core64<64>(Ab, Bb, SEQ, SEQ, SEQ, As, Bs, acc);

    const int lane = threadIdx.x & 63;
    const int wave = threadIdx.x >> 6;
    const int wm = (wave >> 1) * 32, wn = (wave & 1) * 64;
    const int rowBase = by * 64 + wm + ((lane >> 4) * 4);
    const int colBase = bx * 128 + wn + (lane & 15);
    const float* ls = lsum + (size_t)bz * SEQ;
#pragma unroll
    for (int mi = 0; mi < 2; ++mi)
#pragma unroll
        for (int rr = 0; rr < 4; ++rr) {
            const float inv = __builtin_amdgcn_rcpf(ls[rowBase + mi * 16 + rr]);
#pragma unroll
            for (int ni = 0; ni < 4; ++ni)
                Cb[(size_t)(rowBase + mi * 16 + rr) * DIM + colBase + ni * 16] =
                    acc[mi][ni][rr] * inv;
        }
}

// ---------------------------------------------------------------------------
// Fused prep: blocks [0,8192) cast x fp32->bf16; blocks [8192,11264) transpose
// + cast weights (3 x 1024 32x32 tiles); block 11264 zeroes lsum.
// All branches block-uniform.
// ---------------------------------------------------------------------------
__global__ __launch_bounds__(256) void prep(
    const float* __restrict__ x,  const float* __restrict__ wq,
    const float* __restrict__ wk, const float* __restrict__ wv,
    bf16* __restrict__ xb, bf16* __restrict__ Wt, float* __restrict__ lsum)
{
    __shared__ float tile[32][33];
    const int b = blockIdx.x;
    const int tid = threadIdx.x;
    if (b < 8192) {
        const size_t i = ((size_t)b * 256 + tid) * 4;
        const float4 v = *(const float4*)(x + i);
        bf16x4 o = { to_bf16(v.x), to_bf16(v.y), to_bf16(v.z), to_bf16(v.w) };
        *(bf16x4*)(xb + i) = o;
    } else if (b < 8192 + 3072) {
        const int t   = b - 8192;
        const int sel = t >> 10;
        const int n0  = (t & 31) * 32;
        const int k0  = ((t >> 5) & 31) * 32;
        const float* w = (sel == 0) ? wq : (sel == 1) ? wk : wv;
        const int tx = tid & 31, ty = tid >> 5;       // ty 0..7
#pragma unroll
        for (int j = 0; j < 32; j += 8)
            tile[ty + j][tx] = w[(size_t)(k0 + ty + j) * 1024 + n0 + tx];
        __syncthreads();
        bf16* dst = Wt + (size_t)sel * 1024 * 1024;
#pragma unroll
        for (int j = 0; j < 32; j += 8)
            dst[(size_t)(n0 + ty + j) * 1024 + k0 + tx] = to_bf16(tile[tx][ty + j]);
    } else {
#pragma unroll
        for (int i = 0; i < 32; ++i)
            lsum[i * 256 + tid] = 0.0f;
    }
}

// ---------------------------------------------------------------------------
extern "C" void kernel_launch(void* const* d_in, const int* in_sizes, int n_in,
                              void* d_out, int out_size, void* d_ws, size_t ws_size,
                              hipStream_t stream)
{
    const float* x  = (const float*)d_in[0];
    const float* wq = (const float*)d_in[1];
    const float* wk = (const float*)d_in[2];
    const float* wv = (const float*)d_in[3];
    float* out = (float*)d_out;
    char* ws = (char*)d_ws;

    // workspace layout (bytes)
    bf16*  xb   = (bf16*)(ws);                   // 16 MB [8192,1024]
    bf16*  Wt   = (bf16*)(ws + (16u << 20));     //  6 MB [3072,1024] (WqT|WkT|WvT)
    bf16*  QK   = (bf16*)(ws + (22u << 20));     // 32 MB [8192,2048]
    bf16*  Vt   = (bf16*)(ws + (54u << 20));     // 16 MB [4][1024][2048]
    bf16*  P    = (bf16*)(ws + (70u << 20));     // 32 MB [4,2048,2048]
    float* lsum = (float*)(ws + (102u << 20));   // 32 KB [8192]

    prep<<<dim3(8192 + 3072 + 1), dim3(256), 0, stream>>>(
        x, wq, wk, wv, xb, Wt, lsum);

    // QK + Vt in one dispatch
    proj_gemm<<<dim3(1536), dim3(256), 0, stream>>>(xb, Wt, QK, Vt);

    // P' = exp(Q @ K^T / 32), row sums -> lsum
    gemm_scores<<<dim3(16, 16, 4), dim3(256), 0, stream>>>(QK, QK + DIM, P, lsum);

    // out = (P' @ Vt^T) / l
    gemm_pv<<<dim3(8, 32, 4), dim3(256), 0, stream>>>(P, Vt, out, lsum);
}